// Round 3
// baseline (252.898 us; speedup 1.0000x reference)
//
#include <hip/hip_runtime.h>
#include <hip/hip_bf16.h>

#define C_DIM 100000
#define NROW 512
#define DDIM 512
#define BN 64
#define BK 64
#define BSTR 72   // LDS row stride (bf16): 144B, 16B-aligned

typedef __attribute__((ext_vector_type(4))) float f32x4;
typedef __attribute__((ext_vector_type(8))) short bf16x8;
typedef __attribute__((ext_vector_type(4))) float f32acc;

// ---------------- kernel 1: inv row norms of W (norm over C per row d) ----------
__global__ __launch_bounds__(256) void cf_knorm(const float* __restrict__ W,
                                                float* __restrict__ inv_norm) {
    const int d = blockIdx.x;
    const float* row = W + (size_t)d * C_DIM;
    float s = 0.f;
    for (int c4 = threadIdx.x; c4 < C_DIM / 4; c4 += 256) {
        f32x4 v = *(const f32x4*)(row + c4 * 4);
        s += v.x * v.x + v.y * v.y + v.z * v.z + v.w * v.w;
    }
    #pragma unroll
    for (int off = 32; off; off >>= 1) s += __shfl_down(s, off, 64);
    __shared__ float wsum[4];
    if ((threadIdx.x & 63) == 0) wsum[threadIdx.x >> 6] = s;
    __syncthreads();
    if (threadIdx.x == 0) {
        float t = wsum[0] + wsum[1] + wsum[2] + wsum[3];
        inv_norm[d] = 1.0f / sqrtf(t);
    }
}

// ------- kernel 2: xs2 = bf16(x * inv_norm) in MFMA-fragment-tiled layout -------
// xs2[((row>>4)*64 + k8)*128 + (row&15)*8 + e]  (row=0..511, col=k8*8+e)
// -> a wave's B-frag load (16 rows x 8 cols x 4 k8-chunks) is 1024B contiguous.
__global__ __launch_bounds__(256) void cf_kxs2(const float* __restrict__ x,
                                               const float* __restrict__ inv_norm,
                                               __hip_bfloat16* __restrict__ xs2) {
    const int idx = blockIdx.x * 256 + threadIdx.x;   // 0..32767
    const int row = idx >> 6;
    const int k8  = idx & 63;
    const float* xp = x + (size_t)row * DDIM + k8 * 8;
    f32x4 v0 = *(const f32x4*)(xp);
    f32x4 v1 = *(const f32x4*)(xp + 4);
    f32x4 s0 = *(const f32x4*)(inv_norm + k8 * 8);
    f32x4 s1 = *(const f32x4*)(inv_norm + k8 * 8 + 4);
    union { __hip_bfloat16 h[8]; bf16x8 v; } p;
    #pragma unroll
    for (int e = 0; e < 4; ++e) p.h[e]     = __float2bfloat16(v0[e] * s0[e]);
    #pragma unroll
    for (int e = 0; e < 4; ++e) p.h[4 + e] = __float2bfloat16(v1[e] * s1[e]);
    *(bf16x8*)(xs2 + ((size_t)((row >> 4) * 64 + k8) * 128 + (row & 15) * 8)) = p.v;
}

// ---------------- kernel 3: target logits, cos_m, final -------------------------
__global__ __launch_bounds__(64) void cf_ktgt(const float* __restrict__ x,
                                              const float* __restrict__ W,
                                              const float* __restrict__ inv_norm,
                                              const int* __restrict__ label,
                                              float* __restrict__ tl,
                                              float* __restrict__ cm,
                                              float* __restrict__ fl) {
    const int i = blockIdx.x;
    const int lane = threadIdx.x;
    const int lab = label[i];
    float s = 0.f;
    for (int d = lane; d < DDIM; d += 64)
        s += x[(size_t)i * DDIM + d] * inv_norm[d] * W[(size_t)d * C_DIM + lab];
    #pragma unroll
    for (int off = 32; off; off >>= 1) s += __shfl_down(s, off, 64);
    if (lane == 0) {
        float t = fminf(fmaxf(s, -1.f), 1.f);
        float sn = sqrtf(fmaxf(1.f - t * t, 0.f));
        float c = t * 0.8775825618903728f - sn * 0.479425538604203f; // cos(th+m)
        tl[i] = t;
        cm[i] = c;
        fl[i] = (t > -0.8775825618903728f) ? c : (t - 0.2397127693021015f);
    }
}

// ---------------- kernel 4: t = 0.01 * mean(target_logit) -----------------------
__global__ __launch_bounds__(512) void cf_kt(const float* __restrict__ tl,
                                             float* __restrict__ tout) {
    float s = tl[threadIdx.x];
    #pragma unroll
    for (int off = 32; off; off >>= 1) s += __shfl_down(s, off, 64);
    __shared__ float w[8];
    if ((threadIdx.x & 63) == 0) w[threadIdx.x >> 6] = s;
    __syncthreads();
    if (threadIdx.x == 0) {
        float tt = 0.f;
        #pragma unroll
        for (int j = 0; j < 8; ++j) tt += w[j];
        tout[0] = 0.01f * (tt / 512.0f);
    }
}

// ---------------- kernel 5: GEMM (bf16 MFMA) + fused epilogue -------------------
// BM=512, BN=64, BK=64, 8 waves. W staged 2-kt-ahead (reg dbuf -> LDS dbuf),
// B-frags 1-kt-ahead in regs from fragment-tiled xs2 (coalesced 1024B loads).
// Raw s_barrier + lgkmcnt(0) only: W/B prefetch loads stay in flight across
// barriers (counted vmcnt via compiler reg-dependency waits).
__global__ __launch_bounds__(512, 2) void cf_kgemm(
    const __hip_bfloat16* __restrict__ xs2,
    const float* __restrict__ W,
    const int* __restrict__ label,
    const float* __restrict__ cosm,
    const float* __restrict__ finl,
    const float* __restrict__ tp,
    float* __restrict__ out) {
    __shared__ __attribute__((aligned(16))) __hip_bfloat16 Bl[2][BN][BSTR];

    const int tid  = threadIdx.x;
    const int wv   = tid >> 6;       // 0..7
    const int lane = tid & 63;
    const int il   = lane & 15;
    const int hi   = lane >> 4;
    const int cb   = blockIdx.x * BN;

    // W staging: thread -> (c = tid&63, k-octet = wv)
    const int cs  = tid & 63;
    const int gcs = cb + cs;
    const bool gok = (gcs < C_DIM);

    f32acc acc[4][4];
    #pragma unroll
    for (int m = 0; m < 4; ++m)
        #pragma unroll
        for (int n = 0; n < 4; ++n)
            acc[m][n] = (f32acc){0.f, 0.f, 0.f, 0.f};

    float wr0[8], wr1[8];
    bf16x8 bb0[8], bb1[8];

    auto loadW = [&](float (&wr)[8], int kt) {
        const float* wp = W + (size_t)(kt * BK + wv * 8) * C_DIM + gcs;
        #pragma unroll
        for (int j = 0; j < 8; ++j)
            wr[j] = gok ? wp[(size_t)j * C_DIM] : 0.f;
    };
    auto writeW = [&](int buf, const float (&wr)[8]) {
        union { __hip_bfloat16 h[8]; bf16x8 v; } p;
        #pragma unroll
        for (int j = 0; j < 8; ++j) p.h[j] = __float2bfloat16(wr[j]);
        *(bf16x8*)&Bl[buf][cs][wv * 8] = p.v;
    };
    auto loadB = [&](bf16x8 (&bb)[8], int kt) {
        #pragma unroll
        for (int n = 0; n < 4; ++n) {
            const __hip_bfloat16* bp = xs2 + (size_t)(wv * 4 + n) * 64 * 128 + lane * 8;
            #pragma unroll
            for (int q = 0; q < 2; ++q)
                bb[n * 2 + q] = *(const bf16x8*)(bp + (size_t)(kt * 8 + q * 4) * 128);
        }
    };
    auto compute = [&](int cur, const bf16x8 (&bb)[8]) {
        #pragma unroll
        for (int q = 0; q < 2; ++q) {
            bf16x8 a[4];
            #pragma unroll
            for (int m = 0; m < 4; ++m)
                a[m] = *(const bf16x8*)&Bl[cur][m * 16 + il][q * 32 + hi * 8];
            #pragma unroll
            for (int m = 0; m < 4; ++m)
                #pragma unroll
                for (int n = 0; n < 4; ++n)
                    acc[m][n] = __builtin_amdgcn_mfma_f32_16x16x32_bf16(a[m], bb[n * 2 + q], acc[m][n], 0, 0, 0);
        }
    };

#define SYNC do { asm volatile("s_waitcnt lgkmcnt(0)" ::: "memory"); \
                  __builtin_amdgcn_s_barrier(); } while (0)

    // prologue
    loadW(wr0, 0);
    loadB(bb0, 0);
    loadW(wr1, 1);
    writeW(0, wr0);           // waits (counted) on wr0 only
    SYNC;

    // 8 phases, fully unrolled; one barrier per K-step, no vmcnt(0) drain
    loadW(wr0, 2); loadB(bb1, 1); writeW(1, wr1); compute(0, bb0); SYNC;  // kt=0
    loadW(wr1, 3); loadB(bb0, 2); writeW(0, wr0); compute(1, bb1); SYNC;  // kt=1
    loadW(wr0, 4); loadB(bb1, 3); writeW(1, wr1); compute(0, bb0); SYNC;  // kt=2
    loadW(wr1, 5); loadB(bb0, 4); writeW(0, wr0); compute(1, bb1); SYNC;  // kt=3
    loadW(wr0, 6); loadB(bb1, 5); writeW(1, wr1); compute(0, bb0); SYNC;  // kt=4
    loadW(wr1, 7); loadB(bb0, 6); writeW(0, wr0); compute(1, bb1); SYNC;  // kt=5
                   loadB(bb1, 7); writeW(1, wr1); compute(0, bb0); SYNC;  // kt=6
                                                  compute(1, bb1);        // kt=7
#undef SYNC

    // fused epilogue: D[c][i]; lane holds i = ib + n*16 + il, c = cb + m*16 + hi*4 + r
    const float t = tp[0];
    const int ib = wv * 64;
    #pragma unroll
    for (int n = 0; n < 4; ++n) {
        const int i = ib + n * 16 + il;
        const float cmv = cosm[i];
        const float flv = finl[i];
        const int lab = label[i];
        float* orow = out + (size_t)i * C_DIM;
        #pragma unroll
        for (int m = 0; m < 4; ++m) {
            const int c0 = cb + m * 16 + hi * 4;
            if (c0 < C_DIM) {
                f32x4 v = acc[m][n];
                f32x4 o;
                #pragma unroll
                for (int r = 0; r < 4; ++r) {
                    float cz = fminf(fmaxf(v[r], -1.f), 1.f);
                    float ov = (cz > cmv) ? cz * (t + cz) : cz;
                    if (c0 + r == lab) ov = flv;
                    o[r] = ov * 64.0f;
                }
                *(f32x4*)(orow + c0) = o;
            }
        }
    }
}

extern "C" void kernel_launch(void* const* d_in, const int* in_sizes, int n_in,
                              void* d_out, int out_size, void* d_ws, size_t ws_size,
                              hipStream_t stream) {
    const float* x   = (const float*)d_in[0];
    const float* W   = (const float*)d_in[1];
    const int* label = (const int*)d_in[2];
    float* out = (float*)d_out;

    char* ws = (char*)d_ws;
    float* inv_norm = (float*)ws;          // 512 f32
    float* tl  = inv_norm + 512;
    float* cm  = tl + 512;
    float* fl  = cm + 512;
    float* tsc = fl + 512;
    __hip_bfloat16* xs2 = (__hip_bfloat16*)(ws + 16384);  // 512*512 bf16 = 512KB

    cf_knorm<<<DDIM, 256, 0, stream>>>(W, inv_norm);
    cf_kxs2<<<128, 256, 0, stream>>>(x, inv_norm, xs2);
    cf_ktgt<<<NROW, 64, 0, stream>>>(x, W, inv_norm, label, tl, cm, fl);
    cf_kt<<<1, 512, 0, stream>>>(tl, tsc);

    const int nblk = (C_DIM + BN - 1) / BN;   // 1563
    cf_kgemm<<<nblk, 512, 0, stream>>>(xs2, W, label, cm, fl, tsc, out);
}

// Round 4
// 160.372 us; speedup vs baseline: 1.5769x; 1.5769x over previous
//
#include <hip/hip_runtime.h>
#include <hip/hip_bf16.h>

#define C_DIM 100000
#define NROW 512
#define DDIM 512
#define BN 64

typedef __attribute__((ext_vector_type(4))) float f32x4;
typedef __attribute__((ext_vector_type(8))) short bf16x8;
typedef __attribute__((ext_vector_type(4))) float f32acc;

// ---------------- kernel 1: inv row norms of W (norm over C per row d) ----------
__global__ __launch_bounds__(256) void cf_knorm(const float* __restrict__ W,
                                                float* __restrict__ inv_norm) {
    const int d = blockIdx.x;
    const float* row = W + (size_t)d * C_DIM;
    float s = 0.f;
    for (int c4 = threadIdx.x; c4 < C_DIM / 4; c4 += 256) {
        f32x4 v = *(const f32x4*)(row + c4 * 4);
        s += v.x * v.x + v.y * v.y + v.z * v.z + v.w * v.w;
    }
    #pragma unroll
    for (int off = 32; off; off >>= 1) s += __shfl_down(s, off, 64);
    __shared__ float wsum[4];
    if ((threadIdx.x & 63) == 0) wsum[threadIdx.x >> 6] = s;
    __syncthreads();
    if (threadIdx.x == 0) {
        float t = wsum[0] + wsum[1] + wsum[2] + wsum[3];
        inv_norm[d] = 1.0f / sqrtf(t);
    }
}

// ------- kernel 2: xs2 = bf16(x * inv_norm) in MFMA-fragment-tiled layout -------
// xs2[((row>>4)*64 + k8)*128 + (row&15)*8 + e]  (row=0..511, col=k8*8+e)
__global__ __launch_bounds__(256) void cf_kxs2(const float* __restrict__ x,
                                               const float* __restrict__ inv_norm,
                                               __hip_bfloat16* __restrict__ xs2) {
    const int idx = blockIdx.x * 256 + threadIdx.x;   // 0..32767
    const int row = idx >> 6;
    const int k8  = idx & 63;
    const float* xp = x + (size_t)row * DDIM + k8 * 8;
    f32x4 v0 = *(const f32x4*)(xp);
    f32x4 v1 = *(const f32x4*)(xp + 4);
    f32x4 s0 = *(const f32x4*)(inv_norm + k8 * 8);
    f32x4 s1 = *(const f32x4*)(inv_norm + k8 * 8 + 4);
    union { __hip_bfloat16 h[8]; bf16x8 v; } p;
    #pragma unroll
    for (int e = 0; e < 4; ++e) p.h[e]     = __float2bfloat16(v0[e] * s0[e]);
    #pragma unroll
    for (int e = 0; e < 4; ++e) p.h[4 + e] = __float2bfloat16(v1[e] * s1[e]);
    *(bf16x8*)(xs2 + ((size_t)((row >> 4) * 64 + k8) * 128 + (row & 15) * 8)) = p.v;
}

// ---------------- kernel 3: target logits, cos_m, final -------------------------
__global__ __launch_bounds__(64) void cf_ktgt(const float* __restrict__ x,
                                              const float* __restrict__ W,
                                              const float* __restrict__ inv_norm,
                                              const int* __restrict__ label,
                                              float* __restrict__ tl,
                                              float* __restrict__ cm,
                                              float* __restrict__ fl) {
    const int i = blockIdx.x;
    const int lane = threadIdx.x;
    const int lab = label[i];
    float s = 0.f;
    for (int d = lane; d < DDIM; d += 64)
        s += x[(size_t)i * DDIM + d] * inv_norm[d] * W[(size_t)d * C_DIM + lab];
    #pragma unroll
    for (int off = 32; off; off >>= 1) s += __shfl_down(s, off, 64);
    if (lane == 0) {
        float t = fminf(fmaxf(s, -1.f), 1.f);
        float sn = sqrtf(fmaxf(1.f - t * t, 0.f));
        float c = t * 0.8775825618903728f - sn * 0.479425538604203f; // cos(th+m)
        tl[i] = t;
        cm[i] = c;
        fl[i] = (t > -0.8775825618903728f) ? c : (t - 0.2397127693021015f);
    }
}

// ---------------- kernel 4: t = 0.01 * mean(target_logit) -----------------------
__global__ __launch_bounds__(512) void cf_kt(const float* __restrict__ tl,
                                             float* __restrict__ tout) {
    float s = tl[threadIdx.x];
    #pragma unroll
    for (int off = 32; off; off >>= 1) s += __shfl_down(s, off, 64);
    __shared__ float w[8];
    if ((threadIdx.x & 63) == 0) w[threadIdx.x >> 6] = s;
    __syncthreads();
    if (threadIdx.x == 0) {
        float tt = 0.f;
        #pragma unroll
        for (int j = 0; j < 8; ++j) tt += w[j];
        tout[0] = 0.01f * (tt / 512.0f);
    }
}

// ---------------- kernel 5: GEMM (bf16 MFMA) + fused epilogue -------------------
// One-shot staging: the ENTIRE W panel (64 cols x 512 K, bf16, XOR-swizzled)
// goes to LDS (exactly 64KB), ONE barrier, then 16 barrier-free K-steps per
// wave: 4 ds_read_b128 + 4 coalesced 1KB xs2-fragment loads (L2) + 16 MFMA,
// register ping-pong on B-frags. No inter-wave coupling in steady state.
__global__ __launch_bounds__(512, 4) void cf_kgemm(
    const __hip_bfloat16* __restrict__ xs2,
    const float* __restrict__ W,
    const int* __restrict__ label,
    const float* __restrict__ cosm,
    const float* __restrict__ finl,
    const float* __restrict__ tp,
    float* __restrict__ out) {
    // Bl element index: c*512 + (q ^ (c&7))*8 + e   (q = k/8, 16B chunk swizzle)
    __shared__ __attribute__((aligned(16))) __hip_bfloat16 Bl[64 * 512];

    const int tid  = threadIdx.x;
    const int wv   = tid >> 6;       // 0..7
    const int lane = tid & 63;
    const int il   = lane & 15;
    const int hi   = lane >> 4;
    const int cb   = blockIdx.x * BN;

    // ---- stage full W panel: thread covers 4 cols x 8 k, two k-halves ----
    {
        const int c4 = (tid & 15) * 4;       // col quad base 0..60
        const int k8 = tid >> 4;             // 0..31
        const bool ok = (cb + c4) < C_DIM;   // C_DIM%4==0 -> quad all-or-nothing
        #pragma unroll
        for (int kk2 = 0; kk2 < 2; ++kk2) {
            const int kb = kk2 * 256 + k8 * 8;
            f32x4 v[8];
            #pragma unroll
            for (int j = 0; j < 8; ++j) {
                if (ok) v[j] = *(const f32x4*)(W + (size_t)(kb + j) * C_DIM + cb + c4);
                else    v[j] = (f32x4){0.f, 0.f, 0.f, 0.f};
            }
            const int q = kk2 * 32 + k8;
            #pragma unroll
            for (int cc = 0; cc < 4; ++cc) {
                const int c = c4 + cc;
                union { __hip_bfloat16 h[8]; bf16x8 b; } p;
                #pragma unroll
                for (int j = 0; j < 8; ++j) p.h[j] = __float2bfloat16(v[j][cc]);
                *(bf16x8*)&Bl[c * 512 + (q ^ (c & 7)) * 8] = p.b;
            }
        }
    }
    __syncthreads();   // the only barrier

    f32acc acc[4][4];
    #pragma unroll
    for (int m = 0; m < 4; ++m)
        #pragma unroll
        for (int n = 0; n < 4; ++n)
            acc[m][n] = (f32acc){0.f, 0.f, 0.f, 0.f};

    // per-m LDS row base (elements), c = m*16 + il
    int crow[4];
    #pragma unroll
    for (int m = 0; m < 4; ++m) crow[m] = (m * 16 + il) * 512;

    auto loadB = [&](bf16x8 (&bb)[4], int kt) {
        #pragma unroll
        for (int n = 0; n < 4; ++n)
            bb[n] = *(const bf16x8*)(xs2 + (size_t)((wv * 4 + n) * 64 + kt * 4 + hi) * 128 + il * 8);
    };
    auto step = [&](const bf16x8 (&bb)[4], int kt) {
        bf16x8 a[4];
        #pragma unroll
        for (int m = 0; m < 4; ++m) {
            const int c = m * 16 + il;
            const int q = (kt * 4 + hi) ^ (c & 7);
            a[m] = *(const bf16x8*)&Bl[crow[m] + q * 8];
        }
        #pragma unroll
        for (int m = 0; m < 4; ++m)
            #pragma unroll
            for (int n = 0; n < 4; ++n)
                acc[m][n] = __builtin_amdgcn_mfma_f32_16x16x32_bf16(a[m], bb[n], acc[m][n], 0, 0, 0);
    };

    bf16x8 b0[4], b1[4];
    loadB(b0, 0);
    #pragma unroll
    for (int kt = 0; kt < 16; kt += 2) {
        if (kt + 1 < 16) loadB(b1, kt + 1);
        step(b0, kt);
        if (kt + 2 < 16) loadB(b0, kt + 2);
        if (kt + 1 < 16) step(b1, kt + 1);
    }

    // fused epilogue: D[c][i]; lane holds i = ib + n*16 + il, c = cb + m*16 + hi*4 + r
    const float t = tp[0];
    const int ib = wv * 64;
    #pragma unroll
    for (int n = 0; n < 4; ++n) {
        const int i = ib + n * 16 + il;
        const float cmv = cosm[i];
        const float flv = finl[i];
        const int lab = label[i];
        float* orow = out + (size_t)i * C_DIM;
        #pragma unroll
        for (int m = 0; m < 4; ++m) {
            const int c0 = cb + m * 16 + hi * 4;
            if (c0 < C_DIM) {
                f32x4 v = acc[m][n];
                f32x4 o;
                #pragma unroll
                for (int r = 0; r < 4; ++r) {
                    float cz = fminf(fmaxf(v[r], -1.f), 1.f);
                    float ov = (cz > cmv) ? cz * (t + cz) : cz;
                    if (c0 + r == lab) ov = flv;
                    o[r] = ov * 64.0f;
                }
                __builtin_nontemporal_store(o, (f32x4*)(orow + c0));
            }
        }
    }
}

extern "C" void kernel_launch(void* const* d_in, const int* in_sizes, int n_in,
                              void* d_out, int out_size, void* d_ws, size_t ws_size,
                              hipStream_t stream) {
    const float* x   = (const float*)d_in[0];
    const float* W   = (const float*)d_in[1];
    const int* label = (const int*)d_in[2];
    float* out = (float*)d_out;

    char* ws = (char*)d_ws;
    float* inv_norm = (float*)ws;          // 512 f32
    float* tl  = inv_norm + 512;
    float* cm  = tl + 512;
    float* fl  = cm + 512;
    float* tsc = fl + 512;
    __hip_bfloat16* xs2 = (__hip_bfloat16*)(ws + 16384);  // 512*512 bf16 = 512KB

    cf_knorm<<<DDIM, 256, 0, stream>>>(W, inv_norm);
    cf_kxs2<<<128, 256, 0, stream>>>(x, inv_norm, xs2);
    cf_ktgt<<<NROW, 64, 0, stream>>>(x, W, inv_norm, label, tl, cm, fl);
    cf_kt<<<1, 512, 0, stream>>>(tl, tsc);

    const int nblk = (C_DIM + BN - 1) / BN;   // 1563
    cf_kgemm<<<nblk, 512, 0, stream>>>(xs2, W, label, cm, fl, tsc, out);
}